// Round 14
// baseline (184.025 us; speedup 1.0000x reference)
//
#include <hip/hip_runtime.h>
#include <hip/hip_fp16.h>

#define BATCH 8
#define S_LOG 9
#define SBUCKET 512          // nodes per bucket
#define KC 256               // max buckets (N <= 131071)
#define CB 1024              // blocks for count/scatter
#define TTILE 2048           // edges per sort tile
#define EPT (TTILE / 256)    // edges per thread per tile
#define MA 8                 // accum sub-blocks per bucket

static inline size_t alignup(size_t x) { return (x + 255) & ~(size_t)255; }

__device__ __forceinline__ unsigned bf16hi(unsigned u) {
    // fp32 -> bf16 (rne), returned in LOW 16 bits
    return (u + 0x7FFFu + ((u >> 16) & 1u)) >> 16;
}

// ---------------- pipeline kernels ----------------

// fused: blocks [0,CB) bucket-count (ballot-leader histogram, NO atomics);
// blocks [CB,...) transpose y -> yT[node] = 8 bf16 (uint4)
__global__ __launch_bounds__(256)
void count_transpose_kernel(const int* __restrict__ ei0, unsigned* __restrict__ counts,
                            const float* __restrict__ y, uint4* __restrict__ yT,
                            int E, int N, int Npad) {
    __shared__ unsigned hw[4][KC];     // per-wave histograms, 4 KB
    int tid = threadIdx.x;
    if (blockIdx.x >= CB) {
        int n = (blockIdx.x - CB) * 256 + tid;
        if (n < Npad) {
            uint4 o = make_uint4(0u, 0u, 0u, 0u);
            if (n < N) {
                unsigned p[8];
#pragma unroll
                for (int b = 0; b < BATCH; ++b)
                    p[b] = bf16hi(__float_as_uint(y[(size_t)b * N + n]));
                o = make_uint4(p[0] | (p[1] << 16), p[2] | (p[3] << 16),
                               p[4] | (p[5] << 16), p[6] | (p[7] << 16));
            }
            yT[n] = o;
        }
        return;
    }
    unsigned lane = tid & 63, wv = tid >> 6;
    for (int i = tid; i < 4 * KC; i += 256) ((unsigned*)hw)[i] = 0u;
    __syncthreads();
    int chunk = (E + CB - 1) / CB;
    int lo = blockIdx.x * chunk;
    int hi = min(lo + chunk, E);
    for (int base_i = lo; base_i < hi; base_i += 256) {
        int i = base_i + tid;
        bool valid = i < hi;
        unsigned k = valid ? ((unsigned)ei0[i] >> S_LOG) : 0u;
        unsigned long long mm = __ballot(valid ? 1 : 0);
#pragma unroll
        for (int b = 0; b < 8; ++b) {
            unsigned long long vb = __ballot((k >> b) & 1u);
            mm &= ((k >> b) & 1u) ? vb : ~vb;
        }
        unsigned rank = __popcll(mm & ((1ull << lane) - 1ull));
        unsigned gsz = __popcll(mm);
        if (valid && rank == 0) hw[wv][k] += gsz;   // plain RMW, distinct k per leader
    }
    __syncthreads();
    counts[(size_t)tid * CB + blockIdx.x] =
        hw[0][tid] + hw[1][tid] + hw[2][tid] + hw[3][tid];   // [bucket][block]
}

// scanB1: one block per bucket — local exclusive prefix of counts[k][0..CB) -> base,
// and bucket total -> tot[k].
__global__ __launch_bounds__(256)
void scanB1_kernel(const unsigned* __restrict__ counts, unsigned* __restrict__ base,
                   unsigned* __restrict__ tot) {
    __shared__ unsigned ssum[256];
    int k = blockIdx.x, tid = threadIdx.x;
    const uint4* row4 = (const uint4*)(counts + (size_t)k * CB);
    uint4 v = row4[tid];
    unsigned lsum = v.x + v.y + v.z + v.w;
    ssum[tid] = lsum;
    __syncthreads();
    for (int off = 1; off < 256; off <<= 1) {
        unsigned u = ssum[tid];
        unsigned a = (tid >= off) ? ssum[tid - off] : 0u;
        __syncthreads();
        ssum[tid] = u + a;
        __syncthreads();
    }
    unsigned ex = ssum[tid] - lsum;
    if (tid == 255) tot[k] = ssum[255];
    uint4 o;
    o.x = ex;
    o.y = ex + v.x;
    o.z = o.y + v.y;
    o.w = o.z + v.z;
    ((uint4*)(base + (size_t)k * CB))[tid] = o;
}

// scanC: one block — exclusive scan of bucket totals -> bb[0..KC], bb[KC]=E
__global__ void scanC_kernel(const unsigned* __restrict__ tot,
                             unsigned* __restrict__ bb, int E, int K) {
    __shared__ unsigned sb[KC];
    int t = threadIdx.x;
    unsigned v = (t < K) ? tot[t] : 0u;
    sb[t] = v;
    __syncthreads();
    for (int off = 1; off < KC; off <<= 1) {
        unsigned u = sb[t];
        unsigned a = (t >= off) ? sb[t - off] : 0u;
        __syncthreads();
        sb[t] = u + a;
        __syncthreads();
    }
    bb[t] = sb[t] - v;
    if (t == KC - 1) bb[KC] = (unsigned)E;
}

// scatter: bucket-sort edges into w0coef records. NO LDS atomics:
// per-wave running counters + ballot rank; cross-wave merge via 256-thread scan.
// record: .x = s1 | s0l<<17 ; .y = bf16(coef)<<16 | bf16(gea)
__global__ __launch_bounds__(256)
void scatter_kernel(const int* __restrict__ ei0, const int* __restrict__ ei1,
                    const float* __restrict__ dw, const float* __restrict__ gea,
                    const unsigned* __restrict__ base, const unsigned* __restrict__ bb,
                    uint2* __restrict__ w0coef, int E) {
    __shared__ unsigned cursor[KC];          // 1 KB
    __shared__ unsigned hw[4][KC];           // 4 KB: per-wave running counts / slot bases
    __shared__ unsigned wsum[4];
    __shared__ uint2 srec[TTILE];            // 16 KB
    __shared__ unsigned char skey[TTILE];    // 2 KB
    int tid = threadIdx.x;
    unsigned lane = tid & 63, wv = tid >> 6;
    cursor[tid] = base[(size_t)tid * CB + blockIdx.x] + bb[tid];
    int chunk = (E + CB - 1) / CB;
    int lo = blockIdx.x * chunk;
    int hi = min(lo + chunk, E);
    __syncthreads();

    for (int tileLo = lo; tileLo < hi; tileLo += TTILE) {
        int tn = min(TTILE, hi - tileLo);
        for (int i = tid; i < 4 * KC; i += 256) ((unsigned*)hw)[i] = 0u;
        __syncthreads();

        unsigned k_r[EPT], w0_r[EPT], pk_r[EPT], rk_r[EPT];
#pragma unroll
        for (int j = 0; j < EPT; ++j) {
            int off = j * 256 + tid;
            bool valid = off < tn;
            k_r[j] = 0xFFFFFFFFu;
            unsigned k = 0u;
            if (valid) {
                int i = tileLo + off;
                int s0v = ei0[i];
                int s1v = ei1[i];
                k = (unsigned)s0v >> S_LOG;
                unsigned s0l = (unsigned)(s0v & (SBUCKET - 1));
                k_r[j] = k;
                w0_r[j] = (unsigned)s1v | (s0l << 17);
                float sig = 1.0f / (1.0f + __expf(-dw[i]));
                unsigned cf = __float_as_uint(sqrtf(sig));
                unsigned gu = __float_as_uint(gea[i]);
                pk_r[j] = (bf16hi(cf) << 16) | bf16hi(gu);
            }
            // ballot-group by k across the wave
            unsigned long long mm = __ballot(valid ? 1 : 0);
#pragma unroll
            for (int b = 0; b < 8; ++b) {
                unsigned long long vb = __ballot((k >> b) & 1u);
                mm &= ((k >> b) & 1u) ? vb : ~vb;
            }
            unsigned rank = __popcll(mm & ((1ull << lane) - 1ull));
            unsigned gsz = __popcll(mm);
            unsigned cur = 0;
            if (valid) cur = hw[wv][k];                       // ds_read (broadcast in group)
            if (valid && rank == 0) hw[wv][k] = cur + gsz;    // leader plain write
            rk_r[j] = cur + rank;                             // rank within (wave, tile)
        }
        __syncthreads();

        // merge: thread t owns bucket t. h totals + tile-exclusive scan + wave offsets.
        unsigned h0 = hw[0][tid], h1 = hw[1][tid], h2 = hw[2][tid], h3 = hw[3][tid];
        unsigned tot_t = h0 + h1 + h2 + h3;
        {
            unsigned v = tot_t;
#pragma unroll
            for (int off = 1; off < 64; off <<= 1) {
                unsigned t2 = __shfl_up(v, off, 64);
                if (lane >= off) v += t2;
            }
            if (lane == 63) wsum[wv] = v;
            __syncthreads();
            unsigned addv = 0;
#pragma unroll
            for (unsigned w = 0; w < 4; ++w)
                if (w < wv) addv += wsum[w];
            unsigned tstart = v + addv - tot_t;   // exclusive over buckets within tile
            hw[0][tid] = tstart;
            hw[1][tid] = tstart + h0;
            hw[2][tid] = tstart + h0 + h1;
            hw[3][tid] = tstart + h0 + h1 + h2;
        }
        __syncthreads();

        // stage records bucket-sorted in LDS
#pragma unroll
        for (int j = 0; j < EPT; ++j)
            if (k_r[j] != 0xFFFFFFFFu) {
                unsigned slot = hw[wv][k_r[j]] + rk_r[j];
                srec[slot] = make_uint2(w0_r[j], pk_r[j]);
                skey[slot] = (unsigned char)k_r[j];
            }
        __syncthreads();

        // coalesced write-out
        for (int i = tid; i < tn; i += 256) {
            uint2 u = srec[i];
            unsigned k = skey[i];
            unsigned pos = cursor[k] + ((unsigned)i - hw[0][k]);
            w0coef[pos] = u;
        }
        __syncthreads();
        cursor[tid] += tot_t;
        __syncthreads();
    }
}

// main accumulation: grid (K, MA) — NO LDS atomics, y0 read from yT via L1.
// Per-wave private accumulators (fp16 pairs for the 8 batches, fp32 for deg);
// duplicates resolved by 9-bit ballot grouping + rank-ordered plain RMW rounds.
__global__ __launch_bounds__(256)
void accum_kernel(const uint2* __restrict__ w0coef, const unsigned* __restrict__ bb,
                  const uint4* __restrict__ yT,
                  float* __restrict__ pdegp, float* __restrict__ pout,
                  int N, int Npad) {
    __shared__ __half2 outw[4][4][SBUCKET];       // 32 KB: [wave][batchpair][node]
    __shared__ float  degw[4][SBUCKET];           // 8 KB:  [wave][node]
    int k = blockIdx.x, m = blockIdx.y, tid = threadIdx.x;
    int n0 = k << S_LOG;
    unsigned lane = tid & 63;
    unsigned wv = tid >> 6;

    for (int i = tid; i < 4 * 4 * SBUCKET; i += 256)
        ((unsigned*)outw)[i] = 0u;
    for (int i = tid; i < 4 * SBUCKET; i += 256)
        ((float*)degw)[i] = 0.0f;
    unsigned lo = bb[k], hi = bb[k + 1];
    unsigned cnt = hi - lo;
    unsigned slice = (cnt + MA - 1) / MA;
    unsigned slo = lo + m * slice;
    unsigned shi = min(slo + slice, hi);
    __syncthreads();

    __half2 (*myout)[SBUCKET] = outw[wv];
    float* mydeg = degw[wv];

    unsigned i0 = slo + tid;
    uint2 z2 = make_uint2(0u, 0u);
    uint2 c0 = z2, c1 = z2, d0 = z2, d1 = z2;
    uint4 zg = make_uint4(0u, 0u, 0u, 0u);
    uint4 g0 = zg, g1 = zg, yg0 = zg, yg1 = zg;
    bool vc0 = i0 < shi,       vc1 = i0 + 256 < shi;
    bool vd0 = i0 + 512 < shi, vd1 = i0 + 768 < shi;
    if (vc0) c0 = w0coef[i0];
    if (vc1) c1 = w0coef[i0 + 256];
    if (vd0) d0 = w0coef[i0 + 512];
    if (vd1) d1 = w0coef[i0 + 768];
    if (vc0) { g0 = yT[c0.x & 0x1FFFFu]; yg0 = yT[n0 + (c0.x >> 17)]; }
    if (vc1) { g1 = yT[c1.x & 0x1FFFFu]; yg1 = yT[n0 + (c1.x >> 17)]; }

    while (__any(vc0)) {
        uint4 h0 = zg, h1 = zg, yh0 = zg, yh1 = zg;
        if (vd0) { h0 = yT[d0.x & 0x1FFFFu]; yh0 = yT[n0 + (d0.x >> 17)]; }
        if (vd1) { h1 = yT[d1.x & 0x1FFFFu]; yh1 = yT[n0 + (d1.x >> 17)]; }
        uint2 e0 = z2, e1 = z2;
        bool ve0 = i0 + 1024 < shi, ve1 = i0 + 1280 < shi;
        if (ve0) e0 = w0coef[i0 + 1024];
        if (ve1) e1 = w0coef[i0 + 1280];

#pragma unroll
        for (int half = 0; half < 2; ++half) {
            bool val = half ? vc1 : vc0;
            uint2 cc = half ? c1 : c0;
            uint4 gg = half ? g1 : g0;
            uint4 y0r = half ? yg1 : yg0;
            unsigned s0l = cc.x >> 17;
            // 9-bit ballot grouping of s0l across the wave
            unsigned long long mm = ~0ull;
#pragma unroll
            for (int b = 0; b < 9; ++b) {
                unsigned long long vb = __ballot((s0l >> b) & 1u);
                mm &= ((s0l >> b) & 1u) ? vb : ~vb;
            }
            unsigned rank = __popcll(mm & ((1ull << lane) - 1ull));
            float cf = __uint_as_float(cc.y & 0xFFFF0000u);
            float ge = __uint_as_float(cc.y << 16);
            float q[8];
            {
                const unsigned yw[4] = {y0r.x, y0r.y, y0r.z, y0r.w};
                const unsigned gw[4] = {gg.x, gg.y, gg.z, gg.w};
#pragma unroll
                for (int p = 0; p < 4; ++p) {
                    float ya = __uint_as_float(yw[p] << 16);
                    float yb = __uint_as_float(yw[p] & 0xFFFF0000u);
                    float ga = __uint_as_float(gw[p] << 16);
                    float gb = __uint_as_float(gw[p] & 0xFFFF0000u);
                    q[2 * p]     = cf * fmaxf(ya - ga, 0.0f);
                    q[2 * p + 1] = cf * fmaxf(yb - gb, 0.0f);
                }
            }
            // rank-ordered plain RMW rounds (no atomics)
            unsigned r = 0;
            bool pending = val;
            while (__any(pending && rank >= r ? 1 : 0)) {
                if (pending && rank == r) {
#pragma unroll
                    for (int p = 0; p < 4; ++p) {
                        float2 f = __half22float2(myout[p][s0l]);
                        f.x += q[2 * p];
                        f.y += q[2 * p + 1];
                        myout[p][s0l] = __floats2half2_rn(f.x, f.y);
                    }
                    mydeg[s0l] += ge;
                    pending = false;
                }
                ++r;
            }
        }

        c0 = d0; c1 = d1; d0 = e0; d1 = e1;
        g0 = h0; g1 = h1; yg0 = yh0; yg1 = yh1;
        vc0 = vd0; vc1 = vd1; vd0 = ve0; vd1 = ve1;
        i0 += 512;
    }
    __syncthreads();

    for (int i = tid; i < SBUCKET; i += 256) {
        float d = degw[0][i] + degw[1][i] + degw[2][i] + degw[3][i];
        pdegp[(size_t)m * Npad + n0 + i] = d;
    }
    for (int i = tid; i < BATCH * SBUCKET; i += 256) {
        int b = i >> S_LOG;
        int j = i & (SBUCKET - 1);
        int p = b >> 1;
        float s = 0.0f;
#pragma unroll
        for (int w = 0; w < 4; ++w) {
            float2 f = __half22float2(outw[w][p][j]);
            s += (b & 1) ? f.y : f.x;
        }
        pout[((size_t)m * BATCH + b) * Npad + n0 + j] = s;
    }
}

// out[b*N+n] = 1 - (sum_m pout) / deg^2, deg = sum_m pdegp. One thread per node.
__global__ __launch_bounds__(256)
void finalize_kernel(const float* __restrict__ pdegp, const float* __restrict__ pout,
                     float* __restrict__ out, int N, int Npad) {
    int n = blockIdx.x * blockDim.x + threadIdx.x;
    if (n >= N) return;
    float d = 0.0f;
#pragma unroll
    for (int m = 0; m < MA; ++m) d += pdegp[(size_t)m * Npad + n];
    float inv = 1.0f / (d * d);
#pragma unroll
    for (int b = 0; b < BATCH; ++b) {
        float s = 0.0f;
#pragma unroll
        for (int m = 0; m < MA; ++m)
            s += pout[((size_t)m * BATCH + b) * Npad + n];
        out[(size_t)b * N + n] = 1.0f - s * inv;
    }
}

// ---------------- fallback (R1 path) ----------------

__global__ void fill_one_kernel(float* __restrict__ out, int n) {
    int i = blockIdx.x * blockDim.x + threadIdx.x;
    if (i < n) out[i] = 1.0f;
}

__global__ void deg_kernel(const float* __restrict__ gea,
                           const int* __restrict__ ei0,
                           float* __restrict__ deg, int E) {
    int e = blockIdx.x * blockDim.x + threadIdx.x;
    if (e < E) atomicAdd(&deg[ei0[e]], gea[e]);
}

__global__ void edge_kernel(const float* __restrict__ y,
                            const float* __restrict__ dw,
                            const int* __restrict__ ei0,
                            const int* __restrict__ ei1,
                            const float* __restrict__ deg,
                            float* __restrict__ out,
                            int E, int N) {
    int e = blockIdx.x * blockDim.x + threadIdx.x;
    if (e >= E) return;
    int s0 = ei0[e];
    int s1 = ei1[e];
    float d = deg[s0];
    float inv = 1.0f / (d * d);
    float sig = 1.0f / (1.0f + __expf(-dw[e]));
    float coef = sqrtf(sig) * inv;
#pragma unroll
    for (int b = 0; b < BATCH; ++b) {
        float y0 = y[(size_t)b * N + s0];
        float y1 = y[(size_t)b * N + s1];
        float gm = coef * fmaxf(y0 - y1, 0.0f);
        if (gm != 0.0f) atomicAdd(&out[(size_t)b * N + s0], -gm);
    }
}

// ---------------- launch ----------------

extern "C" void kernel_launch(void* const* d_in, const int* in_sizes, int n_in,
                              void* d_out, int out_size, void* d_ws, size_t ws_size,
                              hipStream_t stream) {
    const float* y   = (const float*)d_in[0];   // [B,N]
    const float* gea = (const float*)d_in[2];   // [E]
    const float* dw  = (const float*)d_in[3];   // [E]
    const int*   ei  = (const int*)d_in[4];     // [2,E]

    const int E = in_sizes[2];
    const int N = in_sizes[0] / BATCH;
    const int* ei0 = ei;
    const int* ei1 = ei + E;

    const int K = (N + SBUCKET - 1) >> S_LOG;
    const int Npad = K << S_LOG;

    size_t o_yT     = 0;
    size_t o_rcf    = o_yT     + alignup((size_t)Npad * 16);
    size_t o_counts = o_rcf    + alignup((size_t)E * 8);
    size_t o_base   = o_counts + alignup((size_t)KC * CB * 4);
    size_t o_tot    = o_base   + alignup((size_t)KC * CB * 4);
    size_t o_bb     = o_tot    + alignup((size_t)KC * 4);
    size_t o_pdegp  = o_bb     + alignup((size_t)(KC + 1) * 4);
    size_t o_pout   = o_pdegp  + alignup((size_t)MA * Npad * 4);
    size_t need     = o_pout   + alignup((size_t)MA * BATCH * Npad * 4);

    if (K <= KC && N <= 131071 && ws_size >= need) {
        char* w = (char*)d_ws;
        uint4*    yT     = (uint4*)(w + o_yT);
        uint2*    w0coef = (uint2*)(w + o_rcf);
        unsigned* counts = (unsigned*)(w + o_counts);
        unsigned* base   = (unsigned*)(w + o_base);
        unsigned* tot    = (unsigned*)(w + o_tot);
        unsigned* bb     = (unsigned*)(w + o_bb);
        float*    pdegp  = (float*)(w + o_pdegp);
        float*    pout   = (float*)(w + o_pout);

        int tb = (Npad + 255) / 256;
        count_transpose_kernel<<<CB + tb, 256, 0, stream>>>(ei0, counts, y, yT,
                                                            E, N, Npad);
        scanB1_kernel<<<K, 256, 0, stream>>>(counts, base, tot);
        scanC_kernel<<<1, KC, 0, stream>>>(tot, bb, E, K);
        scatter_kernel<<<CB, 256, 0, stream>>>(ei0, ei1, dw, gea, base, bb,
                                               w0coef, E);
        accum_kernel<<<dim3(K, MA), 256, 0, stream>>>(w0coef, bb, yT,
                                                      pdegp, pout, N, Npad);
        finalize_kernel<<<(N + 255) / 256, 256, 0, stream>>>(
            pdegp, pout, (float*)d_out, N, Npad);
    } else {
        float* deg = (float*)d_ws;
        (void)hipMemsetAsync(deg, 0, (size_t)N * sizeof(float), stream);
        fill_one_kernel<<<(out_size + 255) / 256, 256, 0, stream>>>((float*)d_out, out_size);
        deg_kernel<<<(E + 255) / 256, 256, 0, stream>>>(gea, ei0, deg, E);
        edge_kernel<<<(E + 255) / 256, 256, 0, stream>>>(y, dw, ei0, ei1, deg,
                                                         (float*)d_out, E, N);
    }
}

// Round 15
// 174.327 us; speedup vs baseline: 1.0556x; 1.0556x over previous
//
#include <hip/hip_runtime.h>
#include <hip/hip_fp16.h>

#define BATCH 8
#define S_LOG 9
#define SBUCKET 512          // nodes per bucket
#define KC 256               // max buckets (N <= 131071)
#define CB 1024              // blocks for count/scatter
#define TTILE 2048           // edges per sort tile
#define EPT (TTILE / 256)    // edges per thread per tile
#define MA 8                 // accum sub-blocks per bucket

static inline size_t alignup(size_t x) { return (x + 255) & ~(size_t)255; }

__device__ __forceinline__ unsigned bf16hi(unsigned u) {
    // fp32 -> bf16 (rne), returned in LOW 16 bits
    return (u + 0x7FFFu + ((u >> 16) & 1u)) >> 16;
}

// ---------------- pipeline kernels ----------------

// fused: blocks [0,CB) bucket-count (uint LDS atomics — cheap); blocks [CB,...)
// transpose y -> yT[node] = 8 bf16 (uint4)
__global__ __launch_bounds__(256)
void count_transpose_kernel(const int* __restrict__ ei0, unsigned* __restrict__ counts,
                            const float* __restrict__ y, uint4* __restrict__ yT,
                            int E, int N, int Npad) {
    __shared__ unsigned cnt[KC];
    int tid = threadIdx.x;
    if (blockIdx.x >= CB) {
        int n = (blockIdx.x - CB) * 256 + tid;
        if (n < Npad) {
            uint4 o = make_uint4(0u, 0u, 0u, 0u);
            if (n < N) {
                unsigned p[8];
#pragma unroll
                for (int b = 0; b < BATCH; ++b)
                    p[b] = bf16hi(__float_as_uint(y[(size_t)b * N + n]));
                o = make_uint4(p[0] | (p[1] << 16), p[2] | (p[3] << 16),
                               p[4] | (p[5] << 16), p[6] | (p[7] << 16));
            }
            yT[n] = o;
        }
        return;
    }
    cnt[tid] = 0;
    __syncthreads();
    int chunk = (E + CB - 1) / CB;
    int lo = blockIdx.x * chunk;
    int hi = min(lo + chunk, E);
    for (int i = lo + tid; i < hi; i += 256)
        atomicAdd(&cnt[ei0[i] >> S_LOG], 1u);
    __syncthreads();
    counts[(size_t)tid * CB + blockIdx.x] = cnt[tid];   // [bucket][block]
}

// scanB1: one block per bucket — local exclusive prefix of counts[k][0..CB) -> base,
// and bucket total -> tot[k].
__global__ __launch_bounds__(256)
void scanB1_kernel(const unsigned* __restrict__ counts, unsigned* __restrict__ base,
                   unsigned* __restrict__ tot) {
    __shared__ unsigned ssum[256];
    int k = blockIdx.x, tid = threadIdx.x;
    const uint4* row4 = (const uint4*)(counts + (size_t)k * CB);
    uint4 v = row4[tid];
    unsigned lsum = v.x + v.y + v.z + v.w;
    ssum[tid] = lsum;
    __syncthreads();
    for (int off = 1; off < 256; off <<= 1) {
        unsigned u = ssum[tid];
        unsigned a = (tid >= off) ? ssum[tid - off] : 0u;
        __syncthreads();
        ssum[tid] = u + a;
        __syncthreads();
    }
    unsigned ex = ssum[tid] - lsum;
    if (tid == 255) tot[k] = ssum[255];
    uint4 o;
    o.x = ex;
    o.y = ex + v.x;
    o.z = o.y + v.y;
    o.w = o.z + v.z;
    ((uint4*)(base + (size_t)k * CB))[tid] = o;
}

// scanC: one block — exclusive scan of bucket totals -> bb[0..KC], bb[KC]=E
__global__ void scanC_kernel(const unsigned* __restrict__ tot,
                             unsigned* __restrict__ bb, int E, int K) {
    __shared__ unsigned sb[KC];
    int t = threadIdx.x;
    unsigned v = (t < K) ? tot[t] : 0u;
    sb[t] = v;
    __syncthreads();
    for (int off = 1; off < KC; off <<= 1) {
        unsigned u = sb[t];
        unsigned a = (t >= off) ? sb[t - off] : 0u;
        __syncthreads();
        sb[t] = u + a;
        __syncthreads();
    }
    bb[t] = sb[t] - v;
    if (t == KC - 1) bb[KC] = (unsigned)E;
}

// scatter: bucket-sort edges into w0coef records (uint LDS atomics — cheap).
// record: .x = s1 | s0l<<17 ; .y = bf16(coef)<<16 | bf16(gea)
__global__ __launch_bounds__(256)
void scatter_kernel(const int* __restrict__ ei0, const int* __restrict__ ei1,
                    const float* __restrict__ dw, const float* __restrict__ gea,
                    const unsigned* __restrict__ base, const unsigned* __restrict__ bb,
                    uint2* __restrict__ w0coef, int E) {
    __shared__ unsigned cursor[KC];
    __shared__ unsigned h[KC];
    __shared__ unsigned tstart[KC];
    __shared__ unsigned wsum[4];
    __shared__ uint2 srec[TTILE];            // 16 KB
    __shared__ unsigned char skey[TTILE];    // 2 KB
    int tid = threadIdx.x;
    cursor[tid] = base[(size_t)tid * CB + blockIdx.x] + bb[tid];
    int chunk = (E + CB - 1) / CB;
    int lo = blockIdx.x * chunk;
    int hi = min(lo + chunk, E);
    __syncthreads();

    for (int tileLo = lo; tileLo < hi; tileLo += TTILE) {
        int tn = min(TTILE, hi - tileLo);
        h[tid] = 0;
        __syncthreads();

        unsigned k_r[EPT], w0_r[EPT], pk_r[EPT], rk_r[EPT];
#pragma unroll
        for (int j = 0; j < EPT; ++j) {
            int off = j * 256 + tid;
            k_r[j] = 0xFFFFFFFFu;
            if (off < tn) {
                int i = tileLo + off;
                int s0v = ei0[i];
                int s1v = ei1[i];
                unsigned k = (unsigned)s0v >> S_LOG;
                unsigned s0l = (unsigned)(s0v & (SBUCKET - 1));
                k_r[j] = k;
                w0_r[j] = (unsigned)s1v | (s0l << 17);
                float sig = 1.0f / (1.0f + __expf(-dw[i]));
                unsigned cf = __float_as_uint(sqrtf(sig));
                unsigned gu = __float_as_uint(gea[i]);
                pk_r[j] = (bf16hi(cf) << 16) | bf16hi(gu);
            }
        }
#pragma unroll
        for (int j = 0; j < EPT; ++j)
            if (k_r[j] != 0xFFFFFFFFu) rk_r[j] = atomicAdd(&h[k_r[j]], 1u);
        __syncthreads();

        // exclusive scan of h[256] via wave shuffles
        unsigned hv = h[tid];
        unsigned v = hv;
        unsigned lane = tid & 63;
        unsigned wv = tid >> 6;
#pragma unroll
        for (int off = 1; off < 64; off <<= 1) {
            unsigned t = __shfl_up(v, off, 64);
            if (lane >= off) v += t;
        }
        if (lane == 63) wsum[wv] = v;
        __syncthreads();
        unsigned addv = 0;
#pragma unroll
        for (unsigned w = 0; w < 4; ++w)
            if (w < wv) addv += wsum[w];
        tstart[tid] = v + addv - hv;
        __syncthreads();

#pragma unroll
        for (int j = 0; j < EPT; ++j)
            if (k_r[j] != 0xFFFFFFFFu) {
                unsigned slot = tstart[k_r[j]] + rk_r[j];
                srec[slot] = make_uint2(w0_r[j], pk_r[j]);
                skey[slot] = (unsigned char)k_r[j];
            }
        __syncthreads();

        for (int i = tid; i < tn; i += 256) {
            uint2 u = srec[i];
            unsigned k = skey[i];
            unsigned pos = cursor[k] + ((unsigned)i - tstart[k]);
            w0coef[pos] = u;
        }
        __syncthreads();
        cursor[tid] += h[tid];
        __syncthreads();
    }
}

// main accumulation: grid (K, MA) — NO LDS f32 atomics, y0 read from yT via L1.
// Per-wave private accumulators (fp16 pairs for the 8 batches, fp32 for deg);
// duplicates resolved by 9-bit ballot grouping + rank-ordered plain RMW rounds.
__global__ __launch_bounds__(256)
void accum_kernel(const uint2* __restrict__ w0coef, const unsigned* __restrict__ bb,
                  const uint4* __restrict__ yT,
                  float* __restrict__ pdegp, float* __restrict__ pout,
                  int N, int Npad) {
    __shared__ __half2 outw[4][4][SBUCKET];       // 32 KB: [wave][batchpair][node]
    __shared__ float  degw[4][SBUCKET];           // 8 KB:  [wave][node]
    int k = blockIdx.x, m = blockIdx.y, tid = threadIdx.x;
    int n0 = k << S_LOG;
    unsigned lane = tid & 63;
    unsigned wv = tid >> 6;

    for (int i = tid; i < 4 * 4 * SBUCKET; i += 256)
        ((unsigned*)outw)[i] = 0u;
    for (int i = tid; i < 4 * SBUCKET; i += 256)
        ((float*)degw)[i] = 0.0f;
    unsigned lo = bb[k], hi = bb[k + 1];
    unsigned cnt = hi - lo;
    unsigned slice = (cnt + MA - 1) / MA;
    unsigned slo = lo + m * slice;
    unsigned shi = min(slo + slice, hi);
    __syncthreads();

    __half2 (*myout)[SBUCKET] = outw[wv];
    float* mydeg = degw[wv];

    unsigned i0 = slo + tid;
    uint2 z2 = make_uint2(0u, 0u);
    uint2 c0 = z2, c1 = z2, d0 = z2, d1 = z2;
    uint4 zg = make_uint4(0u, 0u, 0u, 0u);
    uint4 g0 = zg, g1 = zg, yg0 = zg, yg1 = zg;
    bool vc0 = i0 < shi,       vc1 = i0 + 256 < shi;
    bool vd0 = i0 + 512 < shi, vd1 = i0 + 768 < shi;
    if (vc0) c0 = w0coef[i0];
    if (vc1) c1 = w0coef[i0 + 256];
    if (vd0) d0 = w0coef[i0 + 512];
    if (vd1) d1 = w0coef[i0 + 768];
    if (vc0) { g0 = yT[c0.x & 0x1FFFFu]; yg0 = yT[n0 + (c0.x >> 17)]; }
    if (vc1) { g1 = yT[c1.x & 0x1FFFFu]; yg1 = yT[n0 + (c1.x >> 17)]; }

    while (__any(vc0)) {
        uint4 h0 = zg, h1 = zg, yh0 = zg, yh1 = zg;
        if (vd0) { h0 = yT[d0.x & 0x1FFFFu]; yh0 = yT[n0 + (d0.x >> 17)]; }
        if (vd1) { h1 = yT[d1.x & 0x1FFFFu]; yh1 = yT[n0 + (d1.x >> 17)]; }
        uint2 e0 = z2, e1 = z2;
        bool ve0 = i0 + 1024 < shi, ve1 = i0 + 1280 < shi;
        if (ve0) e0 = w0coef[i0 + 1024];
        if (ve1) e1 = w0coef[i0 + 1280];

#pragma unroll
        for (int half = 0; half < 2; ++half) {
            bool val = half ? vc1 : vc0;
            uint2 cc = half ? c1 : c0;
            uint4 gg = half ? g1 : g0;
            uint4 y0r = half ? yg1 : yg0;
            unsigned s0l = cc.x >> 17;
            // 9-bit ballot grouping of s0l across the wave
            unsigned long long mm = ~0ull;
#pragma unroll
            for (int b = 0; b < 9; ++b) {
                unsigned long long vb = __ballot((s0l >> b) & 1u);
                mm &= ((s0l >> b) & 1u) ? vb : ~vb;
            }
            unsigned rank = __popcll(mm & ((1ull << lane) - 1ull));
            float cf = __uint_as_float(cc.y & 0xFFFF0000u);
            float ge = __uint_as_float(cc.y << 16);
            float q[8];
            {
                const unsigned yw[4] = {y0r.x, y0r.y, y0r.z, y0r.w};
                const unsigned gw[4] = {gg.x, gg.y, gg.z, gg.w};
#pragma unroll
                for (int p = 0; p < 4; ++p) {
                    float ya = __uint_as_float(yw[p] << 16);
                    float yb = __uint_as_float(yw[p] & 0xFFFF0000u);
                    float ga = __uint_as_float(gw[p] << 16);
                    float gb = __uint_as_float(gw[p] & 0xFFFF0000u);
                    q[2 * p]     = cf * fmaxf(ya - ga, 0.0f);
                    q[2 * p + 1] = cf * fmaxf(yb - gb, 0.0f);
                }
            }
            // rank-ordered plain RMW rounds (no atomics)
            unsigned r = 0;
            bool pending = val;
            while (__any(pending && rank >= r ? 1 : 0)) {
                if (pending && rank == r) {
#pragma unroll
                    for (int p = 0; p < 4; ++p) {
                        float2 f = __half22float2(myout[p][s0l]);
                        f.x += q[2 * p];
                        f.y += q[2 * p + 1];
                        myout[p][s0l] = __floats2half2_rn(f.x, f.y);
                    }
                    mydeg[s0l] += ge;
                    pending = false;
                }
                ++r;
            }
        }

        c0 = d0; c1 = d1; d0 = e0; d1 = e1;
        g0 = h0; g1 = h1; yg0 = yh0; yg1 = yh1;
        vc0 = vd0; vc1 = vd1; vd0 = ve0; vd1 = ve1;
        i0 += 512;
    }
    __syncthreads();

    for (int i = tid; i < SBUCKET; i += 256) {
        float d = degw[0][i] + degw[1][i] + degw[2][i] + degw[3][i];
        pdegp[(size_t)m * Npad + n0 + i] = d;
    }
    for (int i = tid; i < BATCH * SBUCKET; i += 256) {
        int b = i >> S_LOG;
        int j = i & (SBUCKET - 1);
        int p = b >> 1;
        float s = 0.0f;
#pragma unroll
        for (int w = 0; w < 4; ++w) {
            float2 f = __half22float2(outw[w][p][j]);
            s += (b & 1) ? f.y : f.x;
        }
        pout[((size_t)m * BATCH + b) * Npad + n0 + j] = s;
    }
}

// out[b*N+n] = 1 - (sum_m pout) / deg^2, deg = sum_m pdegp. One thread per node.
__global__ __launch_bounds__(256)
void finalize_kernel(const float* __restrict__ pdegp, const float* __restrict__ pout,
                     float* __restrict__ out, int N, int Npad) {
    int n = blockIdx.x * blockDim.x + threadIdx.x;
    if (n >= N) return;
    float d = 0.0f;
#pragma unroll
    for (int m = 0; m < MA; ++m) d += pdegp[(size_t)m * Npad + n];
    float inv = 1.0f / (d * d);
#pragma unroll
    for (int b = 0; b < BATCH; ++b) {
        float s = 0.0f;
#pragma unroll
        for (int m = 0; m < MA; ++m)
            s += pout[((size_t)m * BATCH + b) * Npad + n];
        out[(size_t)b * N + n] = 1.0f - s * inv;
    }
}

// ---------------- fallback (R1 path) ----------------

__global__ void fill_one_kernel(float* __restrict__ out, int n) {
    int i = blockIdx.x * blockDim.x + threadIdx.x;
    if (i < n) out[i] = 1.0f;
}

__global__ void deg_kernel(const float* __restrict__ gea,
                           const int* __restrict__ ei0,
                           float* __restrict__ deg, int E) {
    int e = blockIdx.x * blockDim.x + threadIdx.x;
    if (e < E) atomicAdd(&deg[ei0[e]], gea[e]);
}

__global__ void edge_kernel(const float* __restrict__ y,
                            const float* __restrict__ dw,
                            const int* __restrict__ ei0,
                            const int* __restrict__ ei1,
                            const float* __restrict__ deg,
                            float* __restrict__ out,
                            int E, int N) {
    int e = blockIdx.x * blockDim.x + threadIdx.x;
    if (e >= E) return;
    int s0 = ei0[e];
    int s1 = ei1[e];
    float d = deg[s0];
    float inv = 1.0f / (d * d);
    float sig = 1.0f / (1.0f + __expf(-dw[e]));
    float coef = sqrtf(sig) * inv;
#pragma unroll
    for (int b = 0; b < BATCH; ++b) {
        float y0 = y[(size_t)b * N + s0];
        float y1 = y[(size_t)b * N + s1];
        float gm = coef * fmaxf(y0 - y1, 0.0f);
        if (gm != 0.0f) atomicAdd(&out[(size_t)b * N + s0], -gm);
    }
}

// ---------------- launch ----------------

extern "C" void kernel_launch(void* const* d_in, const int* in_sizes, int n_in,
                              void* d_out, int out_size, void* d_ws, size_t ws_size,
                              hipStream_t stream) {
    const float* y   = (const float*)d_in[0];   // [B,N]
    const float* gea = (const float*)d_in[2];   // [E]
    const float* dw  = (const float*)d_in[3];   // [E]
    const int*   ei  = (const int*)d_in[4];     // [2,E]

    const int E = in_sizes[2];
    const int N = in_sizes[0] / BATCH;
    const int* ei0 = ei;
    const int* ei1 = ei + E;

    const int K = (N + SBUCKET - 1) >> S_LOG;
    const int Npad = K << S_LOG;

    size_t o_yT     = 0;
    size_t o_rcf    = o_yT     + alignup((size_t)Npad * 16);
    size_t o_counts = o_rcf    + alignup((size_t)E * 8);
    size_t o_base   = o_counts + alignup((size_t)KC * CB * 4);
    size_t o_tot    = o_base   + alignup((size_t)KC * CB * 4);
    size_t o_bb     = o_tot    + alignup((size_t)KC * 4);
    size_t o_pdegp  = o_bb     + alignup((size_t)(KC + 1) * 4);
    size_t o_pout   = o_pdegp  + alignup((size_t)MA * Npad * 4);
    size_t need     = o_pout   + alignup((size_t)MA * BATCH * Npad * 4);

    if (K <= KC && N <= 131071 && ws_size >= need) {
        char* w = (char*)d_ws;
        uint4*    yT     = (uint4*)(w + o_yT);
        uint2*    w0coef = (uint2*)(w + o_rcf);
        unsigned* counts = (unsigned*)(w + o_counts);
        unsigned* base   = (unsigned*)(w + o_base);
        unsigned* tot    = (unsigned*)(w + o_tot);
        unsigned* bb     = (unsigned*)(w + o_bb);
        float*    pdegp  = (float*)(w + o_pdegp);
        float*    pout   = (float*)(w + o_pout);

        int tb = (Npad + 255) / 256;
        count_transpose_kernel<<<CB + tb, 256, 0, stream>>>(ei0, counts, y, yT,
                                                            E, N, Npad);
        scanB1_kernel<<<K, 256, 0, stream>>>(counts, base, tot);
        scanC_kernel<<<1, KC, 0, stream>>>(tot, bb, E, K);
        scatter_kernel<<<CB, 256, 0, stream>>>(ei0, ei1, dw, gea, base, bb,
                                               w0coef, E);
        accum_kernel<<<dim3(K, MA), 256, 0, stream>>>(w0coef, bb, yT,
                                                      pdegp, pout, N, Npad);
        finalize_kernel<<<(N + 255) / 256, 256, 0, stream>>>(
            pdegp, pout, (float*)d_out, N, Npad);
    } else {
        float* deg = (float*)d_ws;
        (void)hipMemsetAsync(deg, 0, (size_t)N * sizeof(float), stream);
        fill_one_kernel<<<(out_size + 255) / 256, 256, 0, stream>>>((float*)d_out, out_size);
        deg_kernel<<<(E + 255) / 256, 256, 0, stream>>>(gea, ei0, deg, E);
        edge_kernel<<<(E + 255) / 256, 256, 0, stream>>>(y, dw, ei0, ei1, deg,
                                                         (float*)d_out, E, N);
    }
}

// Round 16
// 168.812 us; speedup vs baseline: 1.0901x; 1.0327x over previous
//
#include <hip/hip_runtime.h>
#include <hip/hip_fp16.h>

#define BATCH 8
#define S_LOG 9
#define SBUCKET 512          // nodes per bucket
#define KC 256               // max buckets (N <= 131071)
#define CB 1024              // blocks for count/scatter
#define TTILE 2048           // edges per sort tile
#define EPT 8                // edges per thread per tile (contiguous)
#define MA 16                // accum sub-blocks per bucket

static inline size_t alignup(size_t x) { return (x + 255) & ~(size_t)255; }

__device__ __forceinline__ unsigned bf16hi(unsigned u) {
    // fp32 -> bf16 (rne), returned in LOW 16 bits
    return (u + 0x7FFFu + ((u >> 16) & 1u)) >> 16;
}

__device__ __forceinline__ int aligned_chunk(int E) {
    return (((E + CB - 1) / CB) + 15) & ~15;    // 16-elem aligned => 64B
}

// ---------------- pipeline kernels ----------------

// fused: blocks [0,CB) bucket-count (int4 loads, uint LDS atomics); blocks [CB,...)
// transpose y -> yT[node] = 8 bf16 (uint4)
__global__ __launch_bounds__(256)
void count_transpose_kernel(const int* __restrict__ ei0, unsigned* __restrict__ counts,
                            const float* __restrict__ y, uint4* __restrict__ yT,
                            int E, int N, int Npad) {
    __shared__ unsigned cnt[KC];
    int tid = threadIdx.x;
    if (blockIdx.x >= CB) {
        int n = (blockIdx.x - CB) * 256 + tid;
        if (n < Npad) {
            uint4 o = make_uint4(0u, 0u, 0u, 0u);
            if (n < N) {
                unsigned p[8];
#pragma unroll
                for (int b = 0; b < BATCH; ++b)
                    p[b] = bf16hi(__float_as_uint(y[(size_t)b * N + n]));
                o = make_uint4(p[0] | (p[1] << 16), p[2] | (p[3] << 16),
                               p[4] | (p[5] << 16), p[6] | (p[7] << 16));
            }
            yT[n] = o;
        }
        return;
    }
    cnt[tid] = 0;
    __syncthreads();
    int chunk = aligned_chunk(E);
    int lo = blockIdx.x * chunk;
    int hi = min(lo + chunk, E);
    for (int bi = lo; bi < hi; bi += 1024) {
        int idx = bi + tid * 4;
        if (idx + 4 <= hi) {
            int4 v = *(const int4*)(ei0 + idx);
            atomicAdd(&cnt[(unsigned)v.x >> S_LOG], 1u);
            atomicAdd(&cnt[(unsigned)v.y >> S_LOG], 1u);
            atomicAdd(&cnt[(unsigned)v.z >> S_LOG], 1u);
            atomicAdd(&cnt[(unsigned)v.w >> S_LOG], 1u);
        } else {
#pragma unroll
            for (int j = 0; j < 4; ++j) {
                int i2 = idx + j;
                if (i2 < hi) atomicAdd(&cnt[(unsigned)ei0[i2] >> S_LOG], 1u);
            }
        }
    }
    __syncthreads();
    counts[(size_t)tid * CB + blockIdx.x] = cnt[tid];   // [bucket][block]
}

// scanB1: one block per bucket — local exclusive prefix of counts[k][0..CB) -> base,
// and bucket total -> tot[k].
__global__ __launch_bounds__(256)
void scanB1_kernel(const unsigned* __restrict__ counts, unsigned* __restrict__ base,
                   unsigned* __restrict__ tot) {
    __shared__ unsigned ssum[256];
    int k = blockIdx.x, tid = threadIdx.x;
    const uint4* row4 = (const uint4*)(counts + (size_t)k * CB);
    uint4 v = row4[tid];
    unsigned lsum = v.x + v.y + v.z + v.w;
    ssum[tid] = lsum;
    __syncthreads();
    for (int off = 1; off < 256; off <<= 1) {
        unsigned u = ssum[tid];
        unsigned a = (tid >= off) ? ssum[tid - off] : 0u;
        __syncthreads();
        ssum[tid] = u + a;
        __syncthreads();
    }
    unsigned ex = ssum[tid] - lsum;
    if (tid == 255) tot[k] = ssum[255];
    uint4 o;
    o.x = ex;
    o.y = ex + v.x;
    o.z = o.y + v.y;
    o.w = o.z + v.z;
    ((uint4*)(base + (size_t)k * CB))[tid] = o;
}

// scanC: one block — exclusive scan of bucket totals -> bb[0..KC], bb[KC]=E
__global__ void scanC_kernel(const unsigned* __restrict__ tot,
                             unsigned* __restrict__ bb, int E, int K) {
    __shared__ unsigned sb[KC];
    int t = threadIdx.x;
    unsigned v = (t < K) ? tot[t] : 0u;
    sb[t] = v;
    __syncthreads();
    for (int off = 1; off < KC; off <<= 1) {
        unsigned u = sb[t];
        unsigned a = (t >= off) ? sb[t - off] : 0u;
        __syncthreads();
        sb[t] = u + a;
        __syncthreads();
    }
    bb[t] = sb[t] - v;
    if (t == KC - 1) bb[KC] = (unsigned)E;
}

// scatter: bucket-sort edges into w0coef records (uint LDS atomics — cheap).
// Per-thread CONTIGUOUS EPT elements => int4/float4 vector loads.
// record: .x = s1 | s0l<<17 ; .y = bf16(coef)<<16 | bf16(gea)
__global__ __launch_bounds__(256)
void scatter_kernel(const int* __restrict__ ei0, const int* __restrict__ ei1,
                    const float* __restrict__ dw, const float* __restrict__ gea,
                    const unsigned* __restrict__ base, const unsigned* __restrict__ bb,
                    uint2* __restrict__ w0coef, int E) {
    __shared__ unsigned cursor[KC];
    __shared__ unsigned h[KC];
    __shared__ unsigned tstart[KC];
    __shared__ unsigned wsum[4];
    __shared__ uint2 srec[TTILE];            // 16 KB
    __shared__ unsigned char skey[TTILE];    // 2 KB
    int tid = threadIdx.x;
    cursor[tid] = base[(size_t)tid * CB + blockIdx.x] + bb[tid];
    int chunk = aligned_chunk(E);
    int lo = blockIdx.x * chunk;
    int hi = min(lo + chunk, E);
    __syncthreads();

    for (int tileLo = lo; tileLo < hi; tileLo += TTILE) {
        int tn = min(TTILE, hi - tileLo);
        h[tid] = 0;
        __syncthreads();

        int base_off = tid * EPT;
        unsigned k_r[EPT], w0_r[EPT], pk_r[EPT], rk_r[EPT];
        int s0a[EPT], s1a[EPT];
        float dwa[EPT], gea_a[EPT];
        bool anyv = base_off < tn;
        if (base_off + EPT <= tn) {
            // vector loads (tileLo 16-aligned, base_off multiple of 8)
            const int4* p0 = (const int4*)(ei0 + tileLo + base_off);
            const int4* p1 = (const int4*)(ei1 + tileLo + base_off);
            const float4* pd = (const float4*)(dw + tileLo + base_off);
            const float4* pg = (const float4*)(gea + tileLo + base_off);
            int4 a0 = p0[0], a1 = p0[1];
            int4 b0 = p1[0], b1 = p1[1];
            float4 d0 = pd[0], d1 = pd[1];
            float4 g0 = pg[0], g1 = pg[1];
            s0a[0]=a0.x; s0a[1]=a0.y; s0a[2]=a0.z; s0a[3]=a0.w;
            s0a[4]=a1.x; s0a[5]=a1.y; s0a[6]=a1.z; s0a[7]=a1.w;
            s1a[0]=b0.x; s1a[1]=b0.y; s1a[2]=b0.z; s1a[3]=b0.w;
            s1a[4]=b1.x; s1a[5]=b1.y; s1a[6]=b1.z; s1a[7]=b1.w;
            dwa[0]=d0.x; dwa[1]=d0.y; dwa[2]=d0.z; dwa[3]=d0.w;
            dwa[4]=d1.x; dwa[5]=d1.y; dwa[6]=d1.z; dwa[7]=d1.w;
            gea_a[0]=g0.x; gea_a[1]=g0.y; gea_a[2]=g0.z; gea_a[3]=g0.w;
            gea_a[4]=g1.x; gea_a[5]=g1.y; gea_a[6]=g1.z; gea_a[7]=g1.w;
#pragma unroll
            for (int j = 0; j < EPT; ++j) k_r[j] = 0u;   // mark all valid below
#pragma unroll
            for (int j = 0; j < EPT; ++j) {
                unsigned k = (unsigned)s0a[j] >> S_LOG;
                unsigned s0l = (unsigned)(s0a[j] & (SBUCKET - 1));
                k_r[j] = k;
                w0_r[j] = (unsigned)s1a[j] | (s0l << 17);
                float sig = 1.0f / (1.0f + __expf(-dwa[j]));
                pk_r[j] = (bf16hi(__float_as_uint(sqrtf(sig))) << 16) |
                          bf16hi(__float_as_uint(gea_a[j]));
            }
#pragma unroll
            for (int j = 0; j < EPT; ++j)
                rk_r[j] = atomicAdd(&h[k_r[j]], 1u);
        } else {
#pragma unroll
            for (int j = 0; j < EPT; ++j) {
                int off = base_off + j;
                k_r[j] = 0xFFFFFFFFu;
                if (off < tn) {
                    int i = tileLo + off;
                    int s0v = ei0[i];
                    int s1v = ei1[i];
                    unsigned k = (unsigned)s0v >> S_LOG;
                    unsigned s0l = (unsigned)(s0v & (SBUCKET - 1));
                    k_r[j] = k;
                    w0_r[j] = (unsigned)s1v | (s0l << 17);
                    float sig = 1.0f / (1.0f + __expf(-dw[i]));
                    pk_r[j] = (bf16hi(__float_as_uint(sqrtf(sig))) << 16) |
                              bf16hi(__float_as_uint(gea[i]));
                }
            }
#pragma unroll
            for (int j = 0; j < EPT; ++j)
                if (k_r[j] != 0xFFFFFFFFu) rk_r[j] = atomicAdd(&h[k_r[j]], 1u);
        }
        bool fullv = base_off + EPT <= tn;
        __syncthreads();

        // exclusive scan of h[256] via wave shuffles
        unsigned hv = h[tid];
        unsigned v = hv;
        unsigned lane = tid & 63;
        unsigned wv = tid >> 6;
#pragma unroll
        for (int off = 1; off < 64; off <<= 1) {
            unsigned t = __shfl_up(v, off, 64);
            if (lane >= off) v += t;
        }
        if (lane == 63) wsum[wv] = v;
        __syncthreads();
        unsigned addv = 0;
#pragma unroll
        for (unsigned w = 0; w < 4; ++w)
            if (w < wv) addv += wsum[w];
        tstart[tid] = v + addv - hv;
        __syncthreads();

        if (fullv) {
#pragma unroll
            for (int j = 0; j < EPT; ++j) {
                unsigned slot = tstart[k_r[j]] + rk_r[j];
                srec[slot] = make_uint2(w0_r[j], pk_r[j]);
                skey[slot] = (unsigned char)k_r[j];
            }
        } else if (anyv) {
#pragma unroll
            for (int j = 0; j < EPT; ++j)
                if (k_r[j] != 0xFFFFFFFFu) {
                    unsigned slot = tstart[k_r[j]] + rk_r[j];
                    srec[slot] = make_uint2(w0_r[j], pk_r[j]);
                    skey[slot] = (unsigned char)k_r[j];
                }
        }
        __syncthreads();

        for (int i = tid; i < tn; i += 256) {
            uint2 u = srec[i];
            unsigned k = skey[i];
            unsigned pos = cursor[k] + ((unsigned)i - tstart[k]);
            w0coef[pos] = u;
        }
        __syncthreads();
        cursor[tid] += h[tid];
        __syncthreads();
    }
}

// main accumulation: grid (K, MA), 128 threads (2 waves) — NO LDS f32 atomics.
// Per-wave private fp16-pair accumulators; duplicates resolved by 9-bit ballot
// grouping + rank-ordered plain RMW rounds. y0 read from yT via L1.
__global__ __launch_bounds__(128)
void accum_kernel(const uint2* __restrict__ w0coef, const unsigned* __restrict__ bb,
                  const uint4* __restrict__ yT,
                  float* __restrict__ pdegp, __half2* __restrict__ pout,
                  int N, int Npad) {
    __shared__ __half2 outw[2][4][SBUCKET];       // 16 KB: [wave][batchpair][node]
    __shared__ float  degw[2][SBUCKET];           // 4 KB:  [wave][node]
    int k = blockIdx.x, m = blockIdx.y, tid = threadIdx.x;
    int n0 = k << S_LOG;
    unsigned lane = tid & 63;
    unsigned wv = tid >> 6;

    for (int i = tid; i < 2 * 4 * SBUCKET; i += 128)
        ((unsigned*)outw)[i] = 0u;
    for (int i = tid; i < 2 * SBUCKET; i += 128)
        ((float*)degw)[i] = 0.0f;
    unsigned lo = bb[k], hi = bb[k + 1];
    unsigned cnt = hi - lo;
    unsigned slice = (cnt + MA - 1) / MA;
    unsigned slo = lo + m * slice;
    unsigned shi = min(slo + slice, hi);
    __syncthreads();

    __half2 (*myout)[SBUCKET] = outw[wv];
    float* mydeg = degw[wv];

    unsigned i0 = slo + tid;
    uint2 z2 = make_uint2(0u, 0u);
    uint2 c0 = z2, c1 = z2, d0 = z2, d1 = z2;
    uint4 zg = make_uint4(0u, 0u, 0u, 0u);
    uint4 g0 = zg, g1 = zg, yg0 = zg, yg1 = zg;
    bool vc0 = i0 < shi,       vc1 = i0 + 128 < shi;
    bool vd0 = i0 + 256 < shi, vd1 = i0 + 384 < shi;
    if (vc0) c0 = w0coef[i0];
    if (vc1) c1 = w0coef[i0 + 128];
    if (vd0) d0 = w0coef[i0 + 256];
    if (vd1) d1 = w0coef[i0 + 384];
    if (vc0) { g0 = yT[c0.x & 0x1FFFFu]; yg0 = yT[n0 + (c0.x >> 17)]; }
    if (vc1) { g1 = yT[c1.x & 0x1FFFFu]; yg1 = yT[n0 + (c1.x >> 17)]; }

    while (__any(vc0)) {
        uint4 h0 = zg, h1 = zg, yh0 = zg, yh1 = zg;
        if (vd0) { h0 = yT[d0.x & 0x1FFFFu]; yh0 = yT[n0 + (d0.x >> 17)]; }
        if (vd1) { h1 = yT[d1.x & 0x1FFFFu]; yh1 = yT[n0 + (d1.x >> 17)]; }
        uint2 e0 = z2, e1 = z2;
        bool ve0 = i0 + 512 < shi, ve1 = i0 + 640 < shi;
        if (ve0) e0 = w0coef[i0 + 512];
        if (ve1) e1 = w0coef[i0 + 640];

#pragma unroll
        for (int half = 0; half < 2; ++half) {
            bool val = half ? vc1 : vc0;
            uint2 cc = half ? c1 : c0;
            uint4 gg = half ? g1 : g0;
            uint4 y0r = half ? yg1 : yg0;
            unsigned s0l = cc.x >> 17;
            // 9-bit ballot grouping of s0l across the wave
            unsigned long long mm = ~0ull;
#pragma unroll
            for (int b = 0; b < 9; ++b) {
                unsigned long long vb = __ballot((s0l >> b) & 1u);
                mm &= ((s0l >> b) & 1u) ? vb : ~vb;
            }
            unsigned rank = __popcll(mm & ((1ull << lane) - 1ull));
            float cf = __uint_as_float(cc.y & 0xFFFF0000u);
            float ge = __uint_as_float(cc.y << 16);
            float q[8];
            {
                const unsigned yw[4] = {y0r.x, y0r.y, y0r.z, y0r.w};
                const unsigned gw[4] = {gg.x, gg.y, gg.z, gg.w};
#pragma unroll
                for (int p = 0; p < 4; ++p) {
                    float ya = __uint_as_float(yw[p] << 16);
                    float yb = __uint_as_float(yw[p] & 0xFFFF0000u);
                    float ga = __uint_as_float(gw[p] << 16);
                    float gb = __uint_as_float(gw[p] & 0xFFFF0000u);
                    q[2 * p]     = cf * fmaxf(ya - ga, 0.0f);
                    q[2 * p + 1] = cf * fmaxf(yb - gb, 0.0f);
                }
            }
            // rank-ordered plain RMW rounds (no atomics)
            unsigned r = 0;
            bool pending = val;
            while (__any(pending && rank >= r ? 1 : 0)) {
                if (pending && rank == r) {
#pragma unroll
                    for (int p = 0; p < 4; ++p) {
                        float2 f = __half22float2(myout[p][s0l]);
                        f.x += q[2 * p];
                        f.y += q[2 * p + 1];
                        myout[p][s0l] = __floats2half2_rn(f.x, f.y);
                    }
                    mydeg[s0l] += ge;
                    pending = false;
                }
                ++r;
            }
        }

        c0 = d0; c1 = d1; d0 = e0; d1 = e1;
        g0 = h0; g1 = h1; yg0 = yh0; yg1 = yh1;
        vc0 = vd0; vc1 = vd1; vd0 = ve0; vd1 = ve1;
        i0 += 256;
    }
    __syncthreads();

    for (int i = tid; i < SBUCKET; i += 128)
        pdegp[(size_t)m * Npad + n0 + i] = degw[0][i] + degw[1][i];
    for (int i = tid; i < 4 * SBUCKET; i += 128) {
        int p = i >> S_LOG;
        int j = i & (SBUCKET - 1);
        float2 a = __half22float2(outw[0][p][j]);
        float2 b = __half22float2(outw[1][p][j]);
        pout[((size_t)m * 4 + p) * Npad + n0 + j] = __floats2half2_rn(a.x + b.x, a.y + b.y);
    }
}

// out[b*N+n] = 1 - (sum_m pout)/deg^2. One thread per node.
__global__ __launch_bounds__(256)
void finalize_kernel(const float* __restrict__ pdegp, const __half2* __restrict__ pout,
                     float* __restrict__ out, int N, int Npad) {
    int n = blockIdx.x * blockDim.x + threadIdx.x;
    if (n >= N) return;
    float d = 0.0f;
#pragma unroll
    for (int m = 0; m < MA; ++m) d += pdegp[(size_t)m * Npad + n];
    float inv = 1.0f / (d * d);
#pragma unroll
    for (int p = 0; p < 4; ++p) {
        float sx = 0.0f, sy = 0.0f;
#pragma unroll
        for (int m = 0; m < MA; ++m) {
            float2 f = __half22float2(pout[((size_t)m * 4 + p) * Npad + n]);
            sx += f.x; sy += f.y;
        }
        out[(size_t)(2 * p) * N + n]     = 1.0f - sx * inv;
        out[(size_t)(2 * p + 1) * N + n] = 1.0f - sy * inv;
    }
}

// ---------------- fallback (R1 path) ----------------

__global__ void fill_one_kernel(float* __restrict__ out, int n) {
    int i = blockIdx.x * blockDim.x + threadIdx.x;
    if (i < n) out[i] = 1.0f;
}

__global__ void deg_kernel(const float* __restrict__ gea,
                           const int* __restrict__ ei0,
                           float* __restrict__ deg, int E) {
    int e = blockIdx.x * blockDim.x + threadIdx.x;
    if (e < E) atomicAdd(&deg[ei0[e]], gea[e]);
}

__global__ void edge_kernel(const float* __restrict__ y,
                            const float* __restrict__ dw,
                            const int* __restrict__ ei0,
                            const int* __restrict__ ei1,
                            const float* __restrict__ deg,
                            float* __restrict__ out,
                            int E, int N) {
    int e = blockIdx.x * blockDim.x + threadIdx.x;
    if (e >= E) return;
    int s0 = ei0[e];
    int s1 = ei1[e];
    float d = deg[s0];
    float inv = 1.0f / (d * d);
    float sig = 1.0f / (1.0f + __expf(-dw[e]));
    float coef = sqrtf(sig) * inv;
#pragma unroll
    for (int b = 0; b < BATCH; ++b) {
        float y0 = y[(size_t)b * N + s0];
        float y1 = y[(size_t)b * N + s1];
        float gm = coef * fmaxf(y0 - y1, 0.0f);
        if (gm != 0.0f) atomicAdd(&out[(size_t)b * N + s0], -gm);
    }
}

// ---------------- launch ----------------

extern "C" void kernel_launch(void* const* d_in, const int* in_sizes, int n_in,
                              void* d_out, int out_size, void* d_ws, size_t ws_size,
                              hipStream_t stream) {
    const float* y   = (const float*)d_in[0];   // [B,N]
    const float* gea = (const float*)d_in[2];   // [E]
    const float* dw  = (const float*)d_in[3];   // [E]
    const int*   ei  = (const int*)d_in[4];     // [2,E]

    const int E = in_sizes[2];
    const int N = in_sizes[0] / BATCH;
    const int* ei0 = ei;
    const int* ei1 = ei + E;

    const int K = (N + SBUCKET - 1) >> S_LOG;
    const int Npad = K << S_LOG;

    size_t o_yT     = 0;
    size_t o_rcf    = o_yT     + alignup((size_t)Npad * 16);
    size_t o_counts = o_rcf    + alignup((size_t)E * 8);
    size_t o_base   = o_counts + alignup((size_t)KC * CB * 4);
    size_t o_tot    = o_base   + alignup((size_t)KC * CB * 4);
    size_t o_bb     = o_tot    + alignup((size_t)KC * 4);
    size_t o_pdegp  = o_bb     + alignup((size_t)(KC + 1) * 4);
    size_t o_pout   = o_pdegp  + alignup((size_t)MA * Npad * 4);
    size_t need     = o_pout   + alignup((size_t)MA * 4 * Npad * 4);

    if (K <= KC && N <= 131071 && ws_size >= need) {
        char* w = (char*)d_ws;
        uint4*    yT     = (uint4*)(w + o_yT);
        uint2*    w0coef = (uint2*)(w + o_rcf);
        unsigned* counts = (unsigned*)(w + o_counts);
        unsigned* base   = (unsigned*)(w + o_base);
        unsigned* tot    = (unsigned*)(w + o_tot);
        unsigned* bb     = (unsigned*)(w + o_bb);
        float*    pdegp  = (float*)(w + o_pdegp);
        __half2*  pout   = (__half2*)(w + o_pout);

        int tb = (Npad + 255) / 256;
        count_transpose_kernel<<<CB + tb, 256, 0, stream>>>(ei0, counts, y, yT,
                                                            E, N, Npad);
        scanB1_kernel<<<K, 256, 0, stream>>>(counts, base, tot);
        scanC_kernel<<<1, KC, 0, stream>>>(tot, bb, E, K);
        scatter_kernel<<<CB, 256, 0, stream>>>(ei0, ei1, dw, gea, base, bb,
                                               w0coef, E);
        accum_kernel<<<dim3(K, MA), 128, 0, stream>>>(w0coef, bb, yT,
                                                      pdegp, pout, N, Npad);
        finalize_kernel<<<(N + 255) / 256, 256, 0, stream>>>(
            pdegp, pout, (float*)d_out, N, Npad);
    } else {
        float* deg = (float*)d_ws;
        (void)hipMemsetAsync(deg, 0, (size_t)N * sizeof(float), stream);
        fill_one_kernel<<<(out_size + 255) / 256, 256, 0, stream>>>((float*)d_out, out_size);
        deg_kernel<<<(E + 255) / 256, 256, 0, stream>>>(gea, ei0, deg, E);
        edge_kernel<<<(E + 255) / 256, 256, 0, stream>>>(y, dw, ei0, ei1, deg,
                                                         (float*)d_out, E, N);
    }
}